// Round 10
// baseline (497.738 us; speedup 1.0000x reference)
//
#include <hip/hip_runtime.h>
#include <hip/hip_bf16.h>

#define MN 16384
#define SPLITS 16
#define KSLICE (MN / SPLITS)     // 1024
#define BK 64
#define NSTEPS (KSLICE / BK)     // 16
#define TROWS 256                // rows per block
#define PSLICE (MN * 128L)       // 2 MB fp8 per P slice

typedef float f32x4 __attribute__((ext_vector_type(4)));
typedef float f32x2 __attribute__((ext_vector_type(2)));
typedef int   i32x4 __attribute__((ext_vector_type(4)));

#define A8S  32768.0f            // adj * 2^15 in [0,2)
#define SB1  64.0f               // support1 * 2^6   (|max| ~190 < 448)
#define SB2  4096.0f             // support2 * 2^12  (|max| ~50  < 448)
#define F1ST 0.0078125f          // 2^-7: P1 = LHpart * 2^14 (typ 11, max ~60)
#define F2ST 0.001953125f        // 2^-9: P2 = LCpart * 2^18 (typ 11, max ~60)
                                 //   (R9's 2^-4 overflowed e4m3: adj-mean path
                                 //    makes LCpart ~4e-5, 20x fluct-only est.)
#define K3SC (1.0f / 16384.0f)   // 2^-14
#define K5SC (1.0f / 262144.0f)  // 2^-18

__device__ __forceinline__ void async16(void* lds, const void* g) {
  __builtin_amdgcn_global_load_lds(
      (const __attribute__((address_space(1))) unsigned int*)g,
      (__attribute__((address_space(3))) unsigned int*)lds, 16, 0, 0);
}

// fp8-fragment order for a [K x 128] operand: byte[(U*128 + col)*8 + j]
// holds fp8(val[k = U*8 + j][col]).  (unit U = k>>3, j = k&7)

// ---------------------------------------------------------------------------
// K1: support1 = x @ W2 -> fp8 e4m3 (x SB1) in fragment order.
// ---------------------------------------------------------------------------
__global__ __launch_bounds__(256)
void k1_xw2(const float* __restrict__ x, const float* __restrict__ W2,
            unsigned char* __restrict__ B1) {
  __shared__ __align__(16) float xs[64 * 128];
  const int t = threadIdx.x;
  const long rowbase = (long)blockIdx.x * 64;
  const f32x4* xg = (const f32x4*)(x + rowbase * 128);
  f32x4* xl = (f32x4*)xs;
#pragma unroll
  for (int i = 0; i < 8; ++i) xl[t + 256 * i] = xg[t + 256 * i];
  __syncthreads();
  const int r0 = (t >> 5) * 8;   // 8 rows per thread (8-aligned)
  const int c0 = (t & 31) * 4;   // 4 cols per thread
  float acc[8][4] = {};
  for (int k = 0; k < 128; k += 4) {
    f32x4 w[4];
#pragma unroll
    for (int kk = 0; kk < 4; ++kk) w[kk] = *(const f32x4*)(W2 + (k + kk) * 128 + c0);
#pragma unroll
    for (int i = 0; i < 8; ++i) {
      f32x4 xv = *(const f32x4*)(xs + (r0 + i) * 128 + k);
#pragma unroll
      for (int kk = 0; kk < 4; ++kk)
#pragma unroll
        for (int j = 0; j < 4; ++j) acc[i][j] += xv[kk] * w[kk][j];
    }
  }
  const long U = (rowbase + r0) >> 3;
  i32x4 wv0, wv1;
#pragma unroll
  for (int j = 0; j < 4; ++j) {
    int lo = __builtin_amdgcn_cvt_pk_fp8_f32(acc[0][j] * SB1, acc[1][j] * SB1, 0, false);
    lo     = __builtin_amdgcn_cvt_pk_fp8_f32(acc[2][j] * SB1, acc[3][j] * SB1, lo, true);
    int hi = __builtin_amdgcn_cvt_pk_fp8_f32(acc[4][j] * SB1, acc[5][j] * SB1, 0, false);
    hi     = __builtin_amdgcn_cvt_pk_fp8_f32(acc[6][j] * SB1, acc[7][j] * SB1, hi, true);
    if (j < 2) { wv0[2 * j] = lo; wv0[2 * j + 1] = hi; }
    else       { wv1[2 * (j - 2)] = lo; wv1[2 * (j - 2) + 1] = hi; }
  }
  *(i32x4*)(B1 + (U * 128 + c0) * 8)      = wv0;
  *(i32x4*)(B1 + (U * 128 + c0) * 8 + 16) = wv1;
}

// ---------------------------------------------------------------------------
// Big kernel v9b — BARRIER-FREE free-running waves (R9 + NaN-scale fix).
// SPLITS=16: whole B-slice (128 KB fp8-frag) resident in LDS. 1024 threads =
// 16 waves, 1 block/CU; one __syncthreads after staging, then NO barriers.
// Each wave streams its 16 rows over 16 K-steps with start phase t=(wid+i)&15
// -> 16 distinct 256B column phases concurrently per CU (DRAM channel
// spread), depth-2 register prefetch per wave.
// AMODE 0: A f32 -> cvt fp8 once; bytes feed MFMA + A8 copy (plain stores ->
//          L3-resident for pass 2).
// AMODE 1: A from A8 copy (1 dwordx4/lane/step, block-contiguous 16 KB/step).
// AMODE 2: AMODE 0 without the copy (ws fallback).
// P written as fp8 (x fstore) row-major per slice.
// ---------------------------------------------------------------------------
template <int AMODE>
__global__ __launch_bounds__(1024, 4)
void big_mm(const float* __restrict__ A, const unsigned char* __restrict__ A8r,
            unsigned char* __restrict__ A8w, const unsigned char* __restrict__ B8,
            float fstore, unsigned char* __restrict__ P8) {
  __shared__ __align__(16) unsigned char Bs[131072];   // full B slice, 128 KB
  const int tid  = threadIdx.x;
  const int wid  = tid >> 6;     // 0..15
  const int lane = tid & 63;
  const int g    = lane >> 4;    // k-group
  const int cl   = lane & 15;    // A-row / B-col / C-col within tile
  const int tile_m = blockIdx.x & 63;
  const int s      = blockIdx.x >> 6;
  const long k0 = (long)s * KSLICE;

  // stage whole B slice (8 rounds x 16 KB); dst WAVE-UNIFORM + per-lane src
  {
    const char* src = (const char*)B8 + (long)s * 131072 +
                      (long)wid * 1024 + (long)lane * 16;
    unsigned char* dst = Bs + wid * 1024;   // wave-uniform; HW adds lane*16
#pragma unroll
    for (int r = 0; r < 8; ++r)
      async16(dst + r * 16384, src + (long)r * 16384);
  }

  const int row = tile_m * TROWS + wid * 16 + cl;
  const float* aptr = nullptr;
  if constexpr (AMODE != 1) aptr = A + (long)row * MN + k0 + 16 * g;
  const long c8base = (long)blockIdx.x * (NSTEPS * 16384L) + (long)tid * 16;

  f32x4 acc[8] = {};

  // depth-2 prefetch of steps (wid), (wid+1)
  f32x4 ab[2][4];
  i32x4 qb[2];
  if constexpr (AMODE == 1) {
    qb[0] = *(const i32x4*)(A8r + c8base + (long)(wid & 15) * 16384);
    qb[1] = *(const i32x4*)(A8r + c8base + (long)((wid + 1) & 15) * 16384);
  } else {
    const float* p0 = aptr + (long)(wid & 15) * BK;
    const float* p1 = aptr + (long)((wid + 1) & 15) * BK;
#pragma unroll
    for (int j = 0; j < 4; ++j) {
      ab[0][j] = *(const f32x4*)(p0 + 4 * j);
      ab[1][j] = *(const f32x4*)(p1 + 4 * j);
    }
  }
  __syncthreads();   // one-time: B staged; after this, waves free-run

#pragma unroll
  for (int i = 0; i < NSTEPS; ++i) {
    const int t = (wid + i) & 15;
    int pk0, pk1, pk2, pk3;
    if constexpr (AMODE == 1) {
      i32x4 q = qb[i & 1];
      if (i + 2 < NSTEPS)
        qb[i & 1] = *(const i32x4*)(A8r + c8base + (long)((wid + i + 2) & 15) * 16384);
      pk0 = q[0]; pk1 = q[1]; pk2 = q[2]; pk3 = q[3];
    } else {
      f32x4 a0 = ab[i & 1][0], a1 = ab[i & 1][1], a2 = ab[i & 1][2], a3 = ab[i & 1][3];
      if (i + 2 < NSTEPS) {
        const float* ap = aptr + (long)((wid + i + 2) & 15) * BK;
#pragma unroll
        for (int j = 0; j < 4; ++j) ab[i & 1][j] = *(const f32x4*)(ap + 4 * j);
      }
      pk0 = __builtin_amdgcn_cvt_pk_fp8_f32(a0[0] * A8S, a0[1] * A8S, 0, false);
      pk0 = __builtin_amdgcn_cvt_pk_fp8_f32(a0[2] * A8S, a0[3] * A8S, pk0, true);
      pk1 = __builtin_amdgcn_cvt_pk_fp8_f32(a1[0] * A8S, a1[1] * A8S, 0, false);
      pk1 = __builtin_amdgcn_cvt_pk_fp8_f32(a1[2] * A8S, a1[3] * A8S, pk1, true);
      pk2 = __builtin_amdgcn_cvt_pk_fp8_f32(a2[0] * A8S, a2[1] * A8S, 0, false);
      pk2 = __builtin_amdgcn_cvt_pk_fp8_f32(a2[2] * A8S, a2[3] * A8S, pk2, true);
      pk3 = __builtin_amdgcn_cvt_pk_fp8_f32(a3[0] * A8S, a3[1] * A8S, 0, false);
      pk3 = __builtin_amdgcn_cvt_pk_fp8_f32(a3[2] * A8S, a3[3] * A8S, pk3, true);
      if constexpr (AMODE == 0) {
        i32x4 st = {pk0, pk1, pk2, pk3};
        *(i32x4*)(A8w + c8base + (long)t * 16384) = st;   // plain: keep in L3
      }
    }
    const long alo = ((long)(unsigned)pk1 << 32) | (unsigned)pk0;
    const long ahi = ((long)(unsigned)pk3 << 32) | (unsigned)pk2;

    // B units u = t*8 + 2g (+1): LDS addr = u*1024 + (16c+cl)*8
    const char* bb = (const char*)Bs + t * 8192 + g * 2048 + cl * 8;
#pragma unroll
    for (int c = 0; c < 8; ++c) {
      long b0 = *(const long*)(bb + c * 128);
      long b1 = *(const long*)(bb + 1024 + c * 128);
      acc[c] = __builtin_amdgcn_mfma_f32_16x16x32_fp8_fp8(alo, b0, acc[c], 0, 0, 0);
      acc[c] = __builtin_amdgcn_mfma_f32_16x16x32_fp8_fp8(ahi, b1, acc[c], 0, 0, 0);
    }
  }

  // C/D layout: col = lane&15, row = 4*(lane>>4)+q.  P8 row-major fp8/slice.
  unsigned char* pb = P8 + (long)s * PSLICE +
                      (long)(tile_m * TROWS + wid * 16) * 128 + cl;
#pragma unroll
  for (int c = 0; c < 8; ++c) {
    int w0 = __builtin_amdgcn_cvt_pk_fp8_f32(acc[c][0] * fstore, acc[c][1] * fstore, 0, false);
    w0     = __builtin_amdgcn_cvt_pk_fp8_f32(acc[c][2] * fstore, acc[c][3] * fstore, w0, true);
#pragma unroll
    for (int q = 0; q < 4; ++q)
      __builtin_nontemporal_store((unsigned char)(((unsigned)w0) >> (8 * q)),
                                  pb + (g * 4 + q) * 128 + 16 * c);
  }
}

// ---------------------------------------------------------------------------
// K3: LH = (sum_s fp8dec(P8[s])) * K3SC + b2 (tile in LDS); then
//     B2 = fp8frag(LH @ W4 * SB2);  R = LH @ res_w^T + res_b + b4
// ---------------------------------------------------------------------------
__global__ __launch_bounds__(256)
void k3_mid(const unsigned char* __restrict__ P8, const float* __restrict__ b2,
            const float* __restrict__ W4, const float* __restrict__ res_w,
            const float* __restrict__ b4, const float* __restrict__ res_b,
            unsigned char* __restrict__ B2, float* __restrict__ Rr) {
  __shared__ __align__(16) float hs[64 * 128];
  const int t = threadIdx.x;
  const long rowbase = (long)blockIdx.x * 64;
  const f32x4* b2v = (const f32x4*)b2;
  f32x4* hl = (f32x4*)hs;
#pragma unroll
  for (int i = 0; i < 8; ++i) {
    const int idx = t + 256 * i;
    const unsigned char* pp = P8 + rowbase * 128 + (long)idx * 4;
    f32x4 v = {};
#pragma unroll
    for (int sl = 0; sl < SPLITS; ++sl) {
      unsigned q = *(const unsigned*)(pp + (long)sl * PSLICE);
      f32x2 lo = __builtin_amdgcn_cvt_pk_f32_fp8(q, false);
      f32x2 hi = __builtin_amdgcn_cvt_pk_f32_fp8(q, true);
      v[0] += lo[0]; v[1] += lo[1]; v[2] += hi[0]; v[3] += hi[1];
    }
    hl[idx] = v * K3SC + b2v[idx & 31];
  }
  __syncthreads();
  const int r0 = (t >> 5) * 8;
  const int c0 = (t & 31) * 4;
  float acc2[8][4] = {};
  float accR[8][4] = {};
  for (int k = 0; k < 128; k += 4) {
    f32x4 w4v[4], rwv[4];
#pragma unroll
    for (int kk = 0; kk < 4; ++kk) w4v[kk] = *(const f32x4*)(W4 + (k + kk) * 128 + c0);
#pragma unroll
    for (int j = 0; j < 4; ++j) rwv[j] = *(const f32x4*)(res_w + (c0 + j) * 128 + k);
#pragma unroll
    for (int i = 0; i < 8; ++i) {
      f32x4 xv = *(const f32x4*)(hs + (r0 + i) * 128 + k);
#pragma unroll
      for (int kk = 0; kk < 4; ++kk)
#pragma unroll
        for (int j = 0; j < 4; ++j) {
          acc2[i][j] += xv[kk] * w4v[kk][j];
          accR[i][j] += xv[kk] * rwv[j][kk];
        }
    }
  }
  const long U = (rowbase + r0) >> 3;
  i32x4 wv0, wv1;
#pragma unroll
  for (int j = 0; j < 4; ++j) {
    int lo = __builtin_amdgcn_cvt_pk_fp8_f32(acc2[0][j] * SB2, acc2[1][j] * SB2, 0, false);
    lo     = __builtin_amdgcn_cvt_pk_fp8_f32(acc2[2][j] * SB2, acc2[3][j] * SB2, lo, true);
    int hi = __builtin_amdgcn_cvt_pk_fp8_f32(acc2[4][j] * SB2, acc2[5][j] * SB2, 0, false);
    hi     = __builtin_amdgcn_cvt_pk_fp8_f32(acc2[6][j] * SB2, acc2[7][j] * SB2, hi, true);
    if (j < 2) { wv0[2 * j] = lo; wv0[2 * j + 1] = hi; }
    else       { wv1[2 * (j - 2)] = lo; wv1[2 * (j - 2) + 1] = hi; }
  }
  *(i32x4*)(B2 + (U * 128 + c0) * 8)      = wv0;
  *(i32x4*)(B2 + (U * 128 + c0) * 8 + 16) = wv1;

  const f32x4 b4v = *(const f32x4*)(b4 + c0);
  const f32x4 rbv = *(const f32x4*)(res_b + c0);
#pragma unroll
  for (int i = 0; i < 8; ++i) {
    f32x4 rv;
#pragma unroll
    for (int j = 0; j < 4; ++j) rv[j] = accR[i][j];
    rv += b4v + rbv;
    *(f32x4*)(Rr + (rowbase + r0 + i) * 128 + c0) = rv;
  }
}

// ---------------------------------------------------------------------------
// K5: out = (sum_s fp8dec(P8[s])) * K5SC + R
// ---------------------------------------------------------------------------
__global__ __launch_bounds__(256)
void k5_out(const unsigned char* __restrict__ P8, const float* __restrict__ Rr,
            float* __restrict__ out) {
  const long i = (long)blockIdx.x * 256 + threadIdx.x;   // f32x4 index
  const unsigned char* pp = P8 + i * 4;
  f32x4 v = {};
#pragma unroll
  for (int sl = 0; sl < SPLITS; ++sl) {
    unsigned q = *(const unsigned*)(pp + (long)sl * PSLICE);
    f32x2 lo = __builtin_amdgcn_cvt_pk_f32_fp8(q, false);
    f32x2 hi = __builtin_amdgcn_cvt_pk_f32_fp8(q, true);
    v[0] += lo[0]; v[1] += lo[1]; v[2] += hi[0]; v[3] += hi[1];
  }
  v = v * K5SC + *((const f32x4*)Rr + i);
  __builtin_nontemporal_store(v, (f32x4*)out + i);
}

extern "C" void kernel_launch(void* const* d_in, const int* in_sizes, int n_in,
                              void* d_out, int out_size, void* d_ws, size_t ws_size,
                              hipStream_t stream) {
  const float* x     = (const float*)d_in[0];
  const float* adj   = (const float*)d_in[1];
  const float* W2    = (const float*)d_in[2];
  const float* b2    = (const float*)d_in[3];
  const float* W4    = (const float*)d_in[4];
  const float* b4    = (const float*)d_in[5];
  const float* res_w = (const float*)d_in[6];
  const float* res_b = (const float*)d_in[7];
  float* out = (float*)d_out;

  char* ws = (char*)d_ws;
  unsigned char* P8 = (unsigned char*)ws;                  // 32 MB fp8 partials
  unsigned char* B1 = (unsigned char*)(ws + (32L << 20));  // 2 MB fp8-frag s1
  unsigned char* B2 = (unsigned char*)(ws + (34L << 20));  // 2 MB fp8-frag s2
  float* Rr = (float*)(ws + (36L << 20));                  // 8 MB residual
  unsigned char* A8 = (unsigned char*)(ws + (44L << 20));  // 256 MB fp8 adj

  const size_t need = (44L << 20) + (size_t)MN * MN;  // 300 MB
  const bool fp8_copy = ws_size >= need;

  const int BIGGRID = SPLITS * (MN / TROWS);  // 1024
  k1_xw2<<<dim3(256), dim3(256), 0, stream>>>(x, W2, B1);
  if (fp8_copy) {
    big_mm<0><<<dim3(BIGGRID), dim3(1024), 0, stream>>>(adj, nullptr, A8, B1, F1ST, P8);
    k3_mid<<<dim3(256), dim3(256), 0, stream>>>(P8, b2, W4, res_w, b4, res_b, B2, Rr);
    big_mm<1><<<dim3(BIGGRID), dim3(1024), 0, stream>>>(nullptr, A8, nullptr, B2, F2ST, P8);
  } else {
    big_mm<2><<<dim3(BIGGRID), dim3(1024), 0, stream>>>(adj, nullptr, nullptr, B1, F1ST, P8);
    k3_mid<<<dim3(256), dim3(256), 0, stream>>>(P8, b2, W4, res_w, b4, res_b, B2, Rr);
    big_mm<2><<<dim3(BIGGRID), dim3(1024), 0, stream>>>(adj, nullptr, nullptr, B2, F2ST, P8);
  }
  k5_out<<<dim3(2048), dim3(256), 0, stream>>>(P8, Rr, out);
}

// Round 11
// 422.235 us; speedup vs baseline: 1.1788x; 1.1788x over previous
//
#include <hip/hip_runtime.h>
#include <hip/hip_bf16.h>

#define MN 16384
#define SPLITS 4
#define KSLICE (MN / SPLITS)     // 4096
#define BK 64
#define NSTEPS (KSLICE / BK)     // 64

typedef float f32x4 __attribute__((ext_vector_type(4)));
typedef int   i32x4 __attribute__((ext_vector_type(4)));

#define A8S 32768.0f             // adj * 2^15 in [0,2)
#define SB1 64.0f                // support1 * 2^6
#define SB2 4096.0f              // support2 * 2^12
#define SC1 (1.0f / (32768.0f * 64.0f))     // 2^-21
#define SC2 (1.0f / (32768.0f * 4096.0f))   // 2^-27

__device__ __forceinline__ void async16(void* lds, const void* g) {
  __builtin_amdgcn_global_load_lds(
      (const __attribute__((address_space(1))) unsigned int*)g,
      (__attribute__((address_space(3))) unsigned int*)lds, 16, 0, 0);
}

// fp8-fragment order for a [K x 128] operand: byte[(U*128 + col)*8 + j]
// holds fp8(val[k = U*8 + j][col]).  (unit U = k>>3, j = k&7)

// ---------------------------------------------------------------------------
// K1: support1 = x @ W2 -> fp8 e4m3 (x SB1) in fragment order.
// ---------------------------------------------------------------------------
__global__ __launch_bounds__(256)
void k1_xw2(const float* __restrict__ x, const float* __restrict__ W2,
            unsigned char* __restrict__ B1) {
  __shared__ __align__(16) float xs[64 * 128];
  const int t = threadIdx.x;
  const long rowbase = (long)blockIdx.x * 64;
  const f32x4* xg = (const f32x4*)(x + rowbase * 128);
  f32x4* xl = (f32x4*)xs;
#pragma unroll
  for (int i = 0; i < 8; ++i) xl[t + 256 * i] = xg[t + 256 * i];
  __syncthreads();
  const int r0 = (t >> 5) * 8;   // 8 rows per thread (8-aligned)
  const int c0 = (t & 31) * 4;   // 4 cols per thread
  float acc[8][4] = {};
  for (int k = 0; k < 128; k += 4) {
    f32x4 w[4];
#pragma unroll
    for (int kk = 0; kk < 4; ++kk) w[kk] = *(const f32x4*)(W2 + (k + kk) * 128 + c0);
#pragma unroll
    for (int i = 0; i < 8; ++i) {
      f32x4 xv = *(const f32x4*)(xs + (r0 + i) * 128 + k);
#pragma unroll
      for (int kk = 0; kk < 4; ++kk)
#pragma unroll
        for (int j = 0; j < 4; ++j) acc[i][j] += xv[kk] * w[kk][j];
    }
  }
  const long U = (rowbase + r0) >> 3;
  i32x4 wv0, wv1;
#pragma unroll
  for (int j = 0; j < 4; ++j) {
    int lo = __builtin_amdgcn_cvt_pk_fp8_f32(acc[0][j] * SB1, acc[1][j] * SB1, 0, false);
    lo     = __builtin_amdgcn_cvt_pk_fp8_f32(acc[2][j] * SB1, acc[3][j] * SB1, lo, true);
    int hi = __builtin_amdgcn_cvt_pk_fp8_f32(acc[4][j] * SB1, acc[5][j] * SB1, 0, false);
    hi     = __builtin_amdgcn_cvt_pk_fp8_f32(acc[6][j] * SB1, acc[7][j] * SB1, hi, true);
    if (j < 2) { wv0[2 * j] = lo; wv0[2 * j + 1] = hi; }
    else       { wv1[2 * (j - 2)] = lo; wv1[2 * (j - 2) + 1] = hi; }
  }
  *(i32x4*)(B1 + (U * 128 + c0) * 8)      = wv0;
  *(i32x4*)(B1 + (U * 128 + c0) * 8 + 16) = wv1;
}

// ---------------------------------------------------------------------------
// Big kernel v10: P[s] = adj[:, k-slice s] @ B, fp8 e4m3 MFMA.
// 512 threads / 8 waves; 128-row tile; grid 512 = 2 blocks/CU (LDS 80 KB).
// A is staged through LDS via global_load_lds with GATHER sources: each
// staging instruction covers 4 rows x 256B contiguous runs (16 lanes/row) —
// 16x coarser per-instruction contiguity than per-lane dwordx4 (R8).
// XOR swizzle piece ^= (row&7)<<4 applied on BOTH the pre-swizzled global
// source and the ds_read (conflict-free b128 reads at the 8-clk floor).
// AMODE 0: A f32 via LDS -> cvt fp8 once; bytes feed MFMA + A8 side-copy.
// AMODE 1: A from fp8 copy (1 dwordx4/lane/step, contiguous; reg prefetch 1).
// AMODE 2: AMODE 0 without the side-copy (ws fallback).
// Sync/step: stage(t+1) issued FIRST (sched_barrier-pinned), one raw
// s_barrier with exact counted vmcnt (stores/prefetch stay in flight).
// ---------------------------------------------------------------------------
template <int AMODE>
__global__ __launch_bounds__(512, 4)
void big_mm(const float* __restrict__ A, const unsigned char* __restrict__ A8r,
            unsigned char* __restrict__ A8w, const unsigned char* __restrict__ B8,
            float sc, float* __restrict__ P) {
  // LDS: B bank0 [0,8K) B bank1 [8K,16K); A bank0 [16K,48K) A bank1 [48K,80K)
  constexpr int LDSSZ = (AMODE == 1) ? 16384 : 81920;
  __shared__ __align__(16) unsigned char LB[LDSSZ];
  const int tid  = threadIdx.x;
  const int wid  = tid >> 6;     // 0..7
  const int lane = tid & 63;
  const int g    = lane >> 4;    // k-group
  const int cl   = lane & 15;    // A-row / B-col / C-col within tile
  const int tile_m = blockIdx.x & 127;
  const int s      = blockIdx.x >> 7;
  const long k0 = (long)s * KSLICE;

  const char* bsrc = (const char*)B8 + k0 * 128 + (long)tid * 16;
  const long c8base = (long)blockIdx.x * (64L * 8192) + (long)tid * 16;

  // A gather-stage sources: instruction q covers rows wid*16+q*4+[0,4)
  const char* asrc[4];
  int aoff[4];                   // ds_read offsets (swizzled), j=0..3
  if constexpr (AMODE != 1) {
    const int rl = lane >> 4;    // 0..3
#pragma unroll
    for (int q = 0; q < 4; ++q) {
      const int row_local = wid * 16 + q * 4 + rl;
      const int piece = ((lane & 15) * 16) ^ ((row_local & 7) << 4);
      asrc[q] = (const char*)A + ((long)(tile_m * 128 + row_local) * MN + k0) * 4 + piece;
    }
    const int row = wid * 16 + cl;
#pragma unroll
    for (int j = 0; j < 4; ++j)
      aoff[j] = 16384 + row * 256 + ((g * 64 + j * 16) ^ ((cl & 7) << 4));
  }

  f32x4 acc[8] = {};

  // prologue: stage step 0 into bank 0; AMODE1: prefetch A8(0); full drain
  if constexpr (AMODE != 1) {
#pragma unroll
    for (int q = 0; q < 4; ++q)
      async16(LB + 16384 + (wid * 4 + q) * 1024, asrc[q]);
  }
  async16(LB + wid * 1024, bsrc);
  i32x4 q8n;
  if constexpr (AMODE == 1) q8n = *(const i32x4*)(A8r + c8base);
  __syncthreads();

  for (int t = 0; t < NSTEPS; ++t) {
    const int bank = t & 1;
    // (1) stage (t+1) FIRST into the other bank
    if (t + 1 < NSTEPS) {
      const int nb = bank ^ 1;
      if constexpr (AMODE != 1) {
#pragma unroll
        for (int q = 0; q < 4; ++q)
          async16(LB + 16384 + nb * 32768 + (wid * 4 + q) * 1024,
                  asrc[q] + (long)(t + 1) * 256);
      }
      async16(LB + nb * 8192 + wid * 1024, bsrc + (long)(t + 1) * 8192);
    }
    __builtin_amdgcn_sched_barrier(0);   // pin stages oldest in VMEM order

    // (2) A fragment -> fp8 pk dwords
    int pk0, pk1, pk2, pk3;
    if constexpr (AMODE == 1) {
      i32x4 q8 = q8n;
      if (t + 1 < NSTEPS)
        q8n = *(const i32x4*)(A8r + c8base + (long)(t + 1) * 8192);
      pk0 = q8[0]; pk1 = q8[1]; pk2 = q8[2]; pk3 = q8[3];
    } else {
      f32x4 ar0 = *(const f32x4*)(LB + bank * 32768 + aoff[0]);
      f32x4 ar1 = *(const f32x4*)(LB + bank * 32768 + aoff[1]);
      f32x4 ar2 = *(const f32x4*)(LB + bank * 32768 + aoff[2]);
      f32x4 ar3 = *(const f32x4*)(LB + bank * 32768 + aoff[3]);
      pk0 = __builtin_amdgcn_cvt_pk_fp8_f32(ar0[0] * A8S, ar0[1] * A8S, 0, false);
      pk0 = __builtin_amdgcn_cvt_pk_fp8_f32(ar0[2] * A8S, ar0[3] * A8S, pk0, true);
      pk1 = __builtin_amdgcn_cvt_pk_fp8_f32(ar1[0] * A8S, ar1[1] * A8S, 0, false);
      pk1 = __builtin_amdgcn_cvt_pk_fp8_f32(ar1[2] * A8S, ar1[3] * A8S, pk1, true);
      pk2 = __builtin_amdgcn_cvt_pk_fp8_f32(ar2[0] * A8S, ar2[1] * A8S, 0, false);
      pk2 = __builtin_amdgcn_cvt_pk_fp8_f32(ar2[2] * A8S, ar2[3] * A8S, pk2, true);
      pk3 = __builtin_amdgcn_cvt_pk_fp8_f32(ar3[0] * A8S, ar3[1] * A8S, 0, false);
      pk3 = __builtin_amdgcn_cvt_pk_fp8_f32(ar3[2] * A8S, ar3[3] * A8S, pk3, true);
      if constexpr (AMODE == 0) {
        i32x4 st = {pk0, pk1, pk2, pk3};
        __builtin_nontemporal_store(st, (i32x4*)(A8w + c8base + (long)t * 8192));
      }
    }
    const long alo = ((long)(unsigned)pk1 << 32) | (unsigned)pk0;
    const long ahi = ((long)(unsigned)pk3 << 32) | (unsigned)pk2;

    // (3) MFMA: 8 col-tiles x 2 k-units (units 2g, 2g+1 of this step)
    const char* bb = (const char*)LB + bank * 8192 + g * 2048 + cl * 8;
#pragma unroll
    for (int c = 0; c < 8; ++c) {
      long b0 = *(const long*)(bb + c * 128);
      long b1 = *(const long*)(bb + 1024 + c * 128);
      acc[c] = __builtin_amdgcn_mfma_f32_16x16x32_fp8_fp8(alo, b0, acc[c], 0, 0, 0);
      acc[c] = __builtin_amdgcn_mfma_f32_16x16x32_fp8_fp8(ahi, b1, acc[c], 0, 0, 0);
    }

    // (4) retire stage(t+1) exactly; keep A8 store / A8 prefetch in flight
    if (t + 1 < NSTEPS) {
      if constexpr (AMODE == 0)      asm volatile("s_waitcnt vmcnt(1)" ::: "memory");
      else if constexpr (AMODE == 2) asm volatile("s_waitcnt vmcnt(0)" ::: "memory");
      else                           asm volatile("s_waitcnt vmcnt(1)" ::: "memory");
      __builtin_amdgcn_s_barrier();
    }
  }

  // C/D layout (HW-verified, dtype-independent): col=lane&15, row=4*(lane>>4)+q
  float* pb = P + ((long)s * MN + tile_m * 128 + wid * 16) * 128;
#pragma unroll
  for (int c = 0; c < 8; ++c)
#pragma unroll
    for (int q = 0; q < 4; ++q)
      __builtin_nontemporal_store(acc[c][q] * sc,
                                  &pb[(g * 4 + q) * 128 + 16 * c + cl]);
}

// ---------------------------------------------------------------------------
// K3: LH = sum_s P[s] + b2 (tile in LDS); then
//     B2 = fp8frag(LH @ W4 * SB2);  R = LH @ res_w^T + res_b + b4
// ---------------------------------------------------------------------------
__global__ __launch_bounds__(256)
void k3_mid(const float* __restrict__ P, const float* __restrict__ b2,
            const float* __restrict__ W4, const float* __restrict__ res_w,
            const float* __restrict__ b4, const float* __restrict__ res_b,
            unsigned char* __restrict__ B2, float* __restrict__ Rr) {
  __shared__ __align__(16) float hs[64 * 128];
  const int t = threadIdx.x;
  const long rowbase = (long)blockIdx.x * 64;
  const long base = rowbase * 32;            // f32x4 units (128/4 per row)
  const f32x4* P0 = (const f32x4*)P + base;
  const f32x4* P1 = (const f32x4*)P + (long)MN * 32 + base;
  const f32x4* P2 = (const f32x4*)P + 2L * MN * 32 + base;
  const f32x4* P3 = (const f32x4*)P + 3L * MN * 32 + base;
  const f32x4* b2v = (const f32x4*)b2;
  f32x4* hl = (f32x4*)hs;
#pragma unroll
  for (int i = 0; i < 8; ++i) {
    int idx = t + 256 * i;
    f32x4 v = __builtin_nontemporal_load(P0 + idx);
    v += __builtin_nontemporal_load(P1 + idx);
    v += __builtin_nontemporal_load(P2 + idx);
    v += __builtin_nontemporal_load(P3 + idx);
    hl[idx] = v + b2v[idx & 31];
  }
  __syncthreads();
  const int r0 = (t >> 5) * 8;
  const int c0 = (t & 31) * 4;
  float acc2[8][4] = {};
  float accR[8][4] = {};
  for (int k = 0; k < 128; k += 4) {
    f32x4 w4v[4], rwv[4];
#pragma unroll
    for (int kk = 0; kk < 4; ++kk) w4v[kk] = *(const f32x4*)(W4 + (k + kk) * 128 + c0);
#pragma unroll
    for (int j = 0; j < 4; ++j) rwv[j] = *(const f32x4*)(res_w + (c0 + j) * 128 + k);
#pragma unroll
    for (int i = 0; i < 8; ++i) {
      f32x4 xv = *(const f32x4*)(hs + (r0 + i) * 128 + k);
#pragma unroll
      for (int kk = 0; kk < 4; ++kk)
#pragma unroll
        for (int j = 0; j < 4; ++j) {
          acc2[i][j] += xv[kk] * w4v[kk][j];
          accR[i][j] += xv[kk] * rwv[j][kk];
        }
    }
  }
  const long U = (rowbase + r0) >> 3;
  i32x4 wv0, wv1;
#pragma unroll
  for (int j = 0; j < 4; ++j) {
    int lo = __builtin_amdgcn_cvt_pk_fp8_f32(acc2[0][j] * SB2, acc2[1][j] * SB2, 0, false);
    lo     = __builtin_amdgcn_cvt_pk_fp8_f32(acc2[2][j] * SB2, acc2[3][j] * SB2, lo, true);
    int hi = __builtin_amdgcn_cvt_pk_fp8_f32(acc2[4][j] * SB2, acc2[5][j] * SB2, 0, false);
    hi     = __builtin_amdgcn_cvt_pk_fp8_f32(acc2[6][j] * SB2, acc2[7][j] * SB2, hi, true);
    if (j < 2) { wv0[2 * j] = lo; wv0[2 * j + 1] = hi; }
    else       { wv1[2 * (j - 2)] = lo; wv1[2 * (j - 2) + 1] = hi; }
  }
  *(i32x4*)(B2 + (U * 128 + c0) * 8)      = wv0;
  *(i32x4*)(B2 + (U * 128 + c0) * 8 + 16) = wv1;

  const f32x4 b4v = *(const f32x4*)(b4 + c0);
  const f32x4 rbv = *(const f32x4*)(res_b + c0);
#pragma unroll
  for (int i = 0; i < 8; ++i) {
    f32x4 rv;
#pragma unroll
    for (int j = 0; j < 4; ++j) rv[j] = accR[i][j];
    rv += b4v + rbv;
    *(f32x4*)(Rr + (rowbase + r0 + i) * 128 + c0) = rv;
  }
}

// ---------------------------------------------------------------------------
// K5: out = sum_s P[s] + R
// ---------------------------------------------------------------------------
__global__ __launch_bounds__(256)
void k5_out(const float* __restrict__ P, const float* __restrict__ Rr,
            float* __restrict__ out) {
  const long i = (long)blockIdx.x * 256 + threadIdx.x;   // f32x4 index
  const f32x4* P0 = (const f32x4*)P;
  const f32x4* P1 = P0 + (long)MN * 32;
  const f32x4* P2 = P0 + 2L * MN * 32;
  const f32x4* P3 = P0 + 3L * MN * 32;
  f32x4 v = __builtin_nontemporal_load(P0 + i);
  v += __builtin_nontemporal_load(P1 + i);
  v += __builtin_nontemporal_load(P2 + i);
  v += __builtin_nontemporal_load(P3 + i);
  v += *((const f32x4*)Rr + i);
  __builtin_nontemporal_store(v, (f32x4*)out + i);
}

extern "C" void kernel_launch(void* const* d_in, const int* in_sizes, int n_in,
                              void* d_out, int out_size, void* d_ws, size_t ws_size,
                              hipStream_t stream) {
  const float* x     = (const float*)d_in[0];
  const float* adj   = (const float*)d_in[1];
  const float* W2    = (const float*)d_in[2];
  const float* b2    = (const float*)d_in[3];
  const float* W4    = (const float*)d_in[4];
  const float* b4    = (const float*)d_in[5];
  const float* res_w = (const float*)d_in[6];
  const float* res_b = (const float*)d_in[7];
  float* out = (float*)d_out;

  char* ws = (char*)d_ws;
  unsigned char* B1 = (unsigned char*)ws;                  // 2 MB fp8-frag s1
  unsigned char* B2 = (unsigned char*)(ws + (4L << 20));   // 2 MB fp8-frag s2
  float* Rr = (float*)(ws + (8L << 20));                   // 8 MB residual
  float* P  = (float*)(ws + (16L << 20));                  // 32 MB f32 partials
  unsigned char* A8 = (unsigned char*)(ws + (48L << 20));  // 256 MB fp8 adj

  const size_t need = (48L << 20) + (size_t)MN * MN;  // 316.8 MB
  const bool fp8_copy = ws_size >= need;

  k1_xw2<<<dim3(256), dim3(256), 0, stream>>>(x, W2, B1);
  if (fp8_copy) {
    big_mm<0><<<dim3(128 * SPLITS), dim3(512), 0, stream>>>(adj, nullptr, A8, B1, SC1, P);
    k3_mid<<<dim3(256), dim3(256), 0, stream>>>(P, b2, W4, res_w, b4, res_b, B2, Rr);
    big_mm<1><<<dim3(128 * SPLITS), dim3(512), 0, stream>>>(nullptr, A8, nullptr, B2, SC2, P);
  } else {
    big_mm<2><<<dim3(128 * SPLITS), dim3(512), 0, stream>>>(adj, nullptr, nullptr, B1, SC1, P);
    k3_mid<<<dim3(256), dim3(256), 0, stream>>>(P, b2, W4, res_w, b4, res_b, B2, Rr);
    big_mm<2><<<dim3(128 * SPLITS), dim3(512), 0, stream>>>(adj, nullptr, nullptr, B2, SC2, P);
  }
  k5_out<<<dim3(2048), dim3(256), 0, stream>>>(P, Rr, out);
}